// Round 6
// baseline (252.203 us; speedup 1.0000x reference)
//
#include <hip/hip_runtime.h>

// Spectral conv, single fused kernel with manual grid barrier:
//   A: xq = interp(x), X-partials P[sc] = xq @ E      (50 sc x 8 cc blocks)
//   B: X = sum_sc P
//   C: Y = channel-mix(X,W); Z[p][s] = sum_m Y[p][m] hat_s(m)
//   D: out = sum_s Re(Z * wf_s e^{2pi i fq_s t_j})
// 512 blocks x 256 thr, LDS ~57KB -> exactly 2 blocks/CU co-resident.

#define NN 4096
#define C1_19 0.9863613034027223   // cos(pi/19)
#define NS3 33
#define NSP 40
#define NBLK 512

// ws float offsets
#define OFF_XRE 0                  // X real [512*64]
#define OFF_XIM 32768
#define OFF_Z   65536              // Z [2][512][NSP]
#define OFF_P   106496             // partials [50][512][128]

__device__ unsigned g_cnt = 0;
__device__ unsigned g_gen = 0;

__device__ __forceinline__ float sin_rev(float r) { return __builtin_amdgcn_sinf(r); }
__device__ __forceinline__ float cos_rev(float r) { return __builtin_amdgcn_cosf(r); }

__device__ __forceinline__ void grid_sync() {
    __syncthreads();
    if (threadIdx.x == 0) {
        __threadfence();
        unsigned g = __hip_atomic_load(&g_gen, __ATOMIC_RELAXED, __HIP_MEMORY_SCOPE_AGENT);
        unsigned a = __hip_atomic_fetch_add(&g_cnt, 1u, __ATOMIC_ACQ_REL, __HIP_MEMORY_SCOPE_AGENT);
        if (a == NBLK - 1u) {
            __hip_atomic_store(&g_cnt, 0u, __ATOMIC_RELAXED, __HIP_MEMORY_SCOPE_AGENT);
            __hip_atomic_fetch_add(&g_gen, 1u, __ATOMIC_RELEASE, __HIP_MEMORY_SCOPE_AGENT);
        } else {
            while (__hip_atomic_load(&g_gen, __ATOMIC_ACQUIRE, __HIP_MEMORY_SCOPE_AGENT) == g)
                __builtin_amdgcn_s_sleep(8);
        }
        __threadfence();
    }
    __syncthreads();
}

struct PhA { float xw[64][93]; float e[2][40][64]; float xqT[40][64]; };
struct PhB { float4 red[8][32]; };
struct PhC { float part[4][2][64]; };
struct PhD { float zt[2][64][41]; float e2[2][NSP][64]; };
union SU { PhA a; PhB b; PhC c; PhD d; };

__global__ __launch_bounds__(256, 2) void k_fused(const float* __restrict__ x,
                                                  const float* __restrict__ wr,
                                                  const float* __restrict__ wi,
                                                  float* __restrict__ out,
                                                  float* __restrict__ ws) {
    __shared__ SU su;
    __shared__ double nd[20], cwd[20];
    __shared__ float qt[40], qa[40], qw[40];
    __shared__ int   qi[40];
    __shared__ float sw0[NS3], sw1[NS3];
    __shared__ int   si0[NS3], si1[NS3];
    __shared__ double sfq[NS3];
    __shared__ float  swf[NS3];
    __shared__ float  yt[2][64];
    const int t = threadIdx.x;
    const int vb = blockIdx.x;

    // ---- tables: CC nodes/weights (libm-free), hat lists, ICFT node lists ----
    if (t == 0) {
        nd[0] = 1.0; nd[1] = C1_19;
        for (int k = 2; k < 20; ++k) nd[k] = 2.0 * C1_19 * nd[k - 1] - nd[k - 2];
    }
    __syncthreads();
    if (t < 20) {
        double v = 1.0;
        for (int j = 1; j <= 9; ++j) {
            int q = (2 * j * t) % 38; if (q > 19) q = 38 - q;
            v -= 2.0 / (4.0 * j * j - 1.0) * nd[q];
        }
        double w = 2.0 * v / 19.0;
        if (t == 0 || t == 19) w *= 0.5;
        cwd[t] = w;
    }
    __syncthreads();
    if (t < NS3) {
        int l = (t < 2) ? 49 : (t < 22 ? 50 : 51);
        int k = (t < 2) ? t : (t < 22 ? t - 2 : t - 13);
        double fq = -2048.0 + ((double)l + 0.5) * 40.95 + 20.475 * nd[k];
        sfq[t] = fq;
        swf[t] = (float)(20.475 * cwd[k]);
        int m0 = (int)floor(fq);
        float fr = (float)(fq - (double)m0);
        sw0[t] = (m0 >= 0 && m0 <= 63) ? (1.f - fr) : 0.f;
        sw1[t] = (m0 + 1 >= 0 && m0 + 1 <= 63) ? fr : 0.f;
        si0[t] = min(max(m0, 0), 63);
        si1[t] = min(max(m0 + 1, 0), 63);
    }

    // ================= phase A: CFT partials =================
    if (vb < 400) {
        const int sc = vb >> 3, cc = vb & 7;
        int i0 = (int)(81.9 * (double)sc) - 2;
        if (i0 < 0) i0 = 0;
        i0 &= ~3;
        if (i0 > 4004) i0 = 4004;
        if (t < 40) {
            int l = 2 * sc + (t >= 20), jn = t % 20;
            double tq = 0.005 * ((double)(2 * l + 1) + nd[jn]);
            double sf = tq * 4095.0;
            int i = (int)sf; if (i > 4094) i = 4094;
            double a = sf - (double)i;
            if (a < 0.0) a = 0.0; if (a > 1.0) a = 1.0;
            qi[t] = i - i0;
            qa[t] = (float)a;
            qt[t] = (float)tq;
            qw[t] = (float)(0.005 * cwd[jn]);
        }
        __syncthreads();
        for (int idx = t; idx < 64 * 23; idx += 256) {
            int row = idx / 23, c4 = idx % 23;
            float4 v = *(const float4*)&x[(size_t)(cc * 64 + row) * NN + i0 + c4 * 4];
            float* d = &su.a.xw[row][c4 * 4];
            d[0] = v.x; d[1] = v.y; d[2] = v.z; d[3] = v.w;
        }
        __syncthreads();
        for (int idx = t; idx < 40 * 64; idx += 256) {
            int s = idx >> 6, m = idx & 63;
            double r = -(double)m * (double)qt[s];
            r -= floor(r);
            float fr = (float)r;
            su.a.e[0][s][m] = qw[s] * cos_rev(fr);
            su.a.e[1][s][m] = qw[s] * sin_rev(fr);
        }
        for (int idx = t; idx < 40 * 64; idx += 256) {
            int q = idx >> 6, r = idx & 63;
            float a = qa[q];
            su.a.xqT[q][r] = (1.f - a) * su.a.xw[r][qi[q]] + a * su.a.xw[r][qi[q] + 1];
        }
        __syncthreads();
        const int mg = t & 15, bg = t >> 4;
        float aR[4][4] = {{0.f}}, aI[4][4] = {{0.f}};
        for (int s = 0; s < 40; ++s) {
            const float4 xv = *(const float4*)&su.a.xqT[s][bg * 4];
            const float4 er = *(const float4*)&su.a.e[0][s][mg * 4];
            const float4 ei = *(const float4*)&su.a.e[1][s][mg * 4];
#pragma unroll
            for (int p = 0; p < 4; ++p) {
                const float xm = (p == 0) ? xv.x : (p == 1) ? xv.y : (p == 2) ? xv.z : xv.w;
                aR[p][0] += xm * er.x; aR[p][1] += xm * er.y;
                aR[p][2] += xm * er.z; aR[p][3] += xm * er.w;
                aI[p][0] += xm * ei.x; aI[p][1] += xm * ei.y;
                aI[p][2] += xm * ei.z; aI[p][3] += xm * ei.w;
            }
        }
        float* P = ws + OFF_P;
#pragma unroll
        for (int p = 0; p < 4; ++p) {
            const size_t row = (size_t)sc * 512 + cc * 64 + bg * 4 + p;
            float4 vr, vi;
            vr.x = aR[p][0]; vr.y = aR[p][1]; vr.z = aR[p][2]; vr.w = aR[p][3];
            vi.x = aI[p][0]; vi.y = aI[p][1]; vi.z = aI[p][2]; vi.w = aI[p][3];
            *(float4*)&P[row * 128 + mg * 4]      = vr;
            *(float4*)&P[row * 128 + 64 + mg * 4] = vi;
        }
    }
    grid_sync();

    // ================= phase B: reduce P -> X =================
    {
        const float4* P4 = (const float4*)(ws + OFF_P);
        const int grp = t >> 5, o = t & 31;
        const int oid = vb * 32 + o;
        float4 s = {0.f, 0.f, 0.f, 0.f};
        for (int kk = grp; kk < 50; kk += 8) {
            float4 v = P4[(size_t)kk * 16384 + oid];
            s.x += v.x; s.y += v.y; s.z += v.z; s.w += v.w;
        }
        su.b.red[grp][o] = s;
        __syncthreads();
        if (t < 32) {
            float4 r = su.b.red[0][t];
#pragma unroll
            for (int g = 1; g < 8; ++g) {
                float4 v = su.b.red[g][t];
                r.x += v.x; r.y += v.y; r.z += v.z; r.w += v.w;
            }
            int od = vb * 32 + t;
            int bc = od >> 5, c4 = od & 31;
            if (c4 < 16) *(float4*)&ws[OFF_XRE + (size_t)bc * 64 + c4 * 4] = r;
            else         *(float4*)&ws[OFF_XIM + (size_t)bc * 64 + (c4 - 16) * 4] = r;
        }
    }
    grid_sync();

    // ================= phase C: mix + Z =================
    {
        const int b = vb >> 6, o = vb & 63;
        const int m = t & 63, grp = t >> 6;
        float yr = 0.f, yi = 0.f;
#pragma unroll 4
        for (int i = grp * 16; i < grp * 16 + 16; ++i) {
            float xr = ws[OFF_XRE + (size_t)(b * 64 + i) * 64 + m];
            float xi = ws[OFF_XIM + (size_t)(b * 64 + i) * 64 + m];
            float a = wr[((size_t)i * 64 + o) * 64 + m];
            float c = wi[((size_t)i * 64 + o) * 64 + m];
            yr += xr * a - xi * c;
            yi += xr * c + xi * a;
        }
        su.c.part[grp][0][m] = yr;
        su.c.part[grp][1][m] = yi;
        __syncthreads();
        if (t < 64) {
            yt[0][t] = ((su.c.part[0][0][t] + su.c.part[1][0][t]) +
                        (su.c.part[2][0][t] + su.c.part[3][0][t]));
            yt[1][t] = ((su.c.part[0][1][t] + su.c.part[1][1][t]) +
                        (su.c.part[2][1][t] + su.c.part[3][1][t]));
        }
        __syncthreads();
        if (t < 2 * NS3) {
            int p = t >= NS3, s = t - p * NS3;
            float z = sw0[s] * yt[p][si0[s]] + sw1[s] * yt[p][si1[s]];
            ws[OFF_Z + (size_t)p * 512 * NSP + ((size_t)b * 64 + o) * NSP + s] = z;
        } else if (t < 2 * NS3 + 14) {
            int u = t - 2 * NS3;
            int p = u / 7, s = NS3 + u % 7;
            ws[OFF_Z + (size_t)p * 512 * NSP + ((size_t)b * 64 + o) * NSP + s] = 0.f;
        }
    }
    grid_sync();

    // ================= phase D: ICFT =================
    {
        const int jt = vb & 63, pc = vb >> 6;
        for (int idx = t; idx < 2 * 64 * NSP; idx += 256) {
            int part = idx / (64 * NSP), rem = idx % (64 * NSP);
            int row = rem / NSP, s = rem % NSP;
            su.d.zt[part][row][s] =
                ws[OFF_Z + (size_t)part * 512 * NSP + ((size_t)pc * 64 + row) * NSP + s];
        }
        __syncthreads();
        const double inv4095 = 1.0 / 4095.0;
        for (int idx = t; idx < NSP * 64; idx += 256) {
            int s = idx >> 6, jl = idx & 63;
            float cr = 0.f, ci = 0.f;
            if (s < NS3) {
                double ph = sfq[s] * ((double)(jt * 64 + jl) * inv4095);
                ph -= floor(ph);
                float fr = (float)ph;
                cr = swf[s] * cos_rev(fr);
                ci = swf[s] * sin_rev(fr);
            }
            su.d.e2[0][s][jl] = cr;
            su.d.e2[1][s][jl] = ci;
        }
        __syncthreads();
        const int jg = t & 15, pg = t >> 4;
        float acc[4][4] = {{0.f}};
        for (int s0 = 0; s0 < NSP; s0 += 8) {
            float zr[4][8], zi[4][8];
#pragma unroll
            for (int p = 0; p < 4; ++p)
#pragma unroll
                for (int u = 0; u < 8; ++u) {
                    zr[p][u] = su.d.zt[0][pg * 4 + p][s0 + u];
                    zi[p][u] = su.d.zt[1][pg * 4 + p][s0 + u];
                }
#pragma unroll
            for (int u = 0; u < 8; ++u) {
                const float4 er = *(const float4*)&su.d.e2[0][s0 + u][jg * 4];
                const float4 ei = *(const float4*)&su.d.e2[1][s0 + u][jg * 4];
#pragma unroll
                for (int p = 0; p < 4; ++p) {
                    acc[p][0] += zr[p][u] * er.x - zi[p][u] * ei.x;
                    acc[p][1] += zr[p][u] * er.y - zi[p][u] * ei.y;
                    acc[p][2] += zr[p][u] * er.z - zi[p][u] * ei.z;
                    acc[p][3] += zr[p][u] * er.w - zi[p][u] * ei.w;
                }
            }
        }
#pragma unroll
        for (int p = 0; p < 4; ++p) {
            float4 r;
            r.x = acc[p][0]; r.y = acc[p][1]; r.z = acc[p][2]; r.w = acc[p][3];
            *(float4*)&out[(size_t)(pc * 64 + pg * 4 + p) * NN + jt * 64 + jg * 4] = r;
        }
    }
}

extern "C" void kernel_launch(void* const* d_in, const int* in_sizes, int n_in,
                              void* d_out, int out_size, void* d_ws, size_t ws_size,
                              hipStream_t stream) {
    const float* x  = (const float*)d_in[0];
    const float* wr = (const float*)d_in[1];
    const float* wi = (const float*)d_in[2];
    float* out = (float*)d_out;
    float* ws  = (float*)d_ws;
    (void)in_sizes; (void)n_in; (void)out_size; (void)ws_size;   // needs ~13 MB

    k_fused<<<NBLK, 256, 0, stream>>>(x, wr, wi, out, ws);
}

// Round 7
// 37.139 us; speedup vs baseline: 6.7907x; 6.7907x over previous
//
#include <hip/hip_runtime.h>

// Spectral conv, factorized:
//   xq = interp(x -> 2000 cheb nodes); X-partials P[sc] = xq @ E (per-block E in LDS)
//   X = sum_sc P;  Y = channel-mix(X,W);  Z[p][s] = sum_m Y[p][m] hat_s(m)
//   out = sum_s Re(Z * wf_s e^{2pi i fq_s t_j})
// v7: same math as v5 (passed, absmax 7.6e-6) with rebalanced grids:
// stage1 800 blocks, reduce 512, mixZ 512 (1 (b,o) pair each), stage3 512.

#define NN 4096
#define C1_19 0.9863613034027223   // cos(pi/19)
#define NS3 33
#define NSP 40

// ws float offsets
#define OFF_XRE 0                  // X real [512*64]
#define OFF_XIM 32768
#define OFF_Z   65536              // Z [2][512][NSP]
#define OFF_P   106496             // partials [50][512][128]

__device__ __forceinline__ float sin_rev(float r) { return __builtin_amdgcn_sinf(r); }
__device__ __forceinline__ float cos_rev(float r) { return __builtin_amdgcn_cosf(r); }

// nd[k] = cos(pi k/19); cwd[k] = CC weight (endpoints halved). No libm.
// Contains one __syncthreads; caller must sync again before using cwd.
__device__ __forceinline__ void build_tables(double* nd, double* cwd, int t) {
    if (t == 0) {
        nd[0] = 1.0; nd[1] = C1_19;
        for (int k = 2; k < 20; ++k) nd[k] = 2.0 * C1_19 * nd[k - 1] - nd[k - 2];
    }
    __syncthreads();
    if (t < 20) {
        double v = 1.0;
        for (int j = 1; j <= 9; ++j) {
            int q = (2 * j * t) % 38; if (q > 19) q = 38 - q;   // cos(2pi j t/19)
            v -= 2.0 / (4.0 * j * j - 1.0) * nd[q];
        }
        double w = 2.0 * v / 19.0;
        if (t == 0 || t == 19) w *= 0.5;
        cwd[t] = w;
    }
}

// ---------- stage 1: P[sc][bc][128] partials; grid (50 sc, 16 cc) ----------
__global__ __launch_bounds__(256) void k_stage1(const float* __restrict__ x,
                                                float* __restrict__ P) {
    __shared__ double nd[20], cwd[20];
    __shared__ float qt[40], qa[40], qw[40];
    __shared__ int   qi[40];
    __shared__ __align__(16) float xw[32][93];
    __shared__ __align__(16) float e[2][40][64];
    __shared__ __align__(16) float xqT[40][32];
    const int t = threadIdx.x;
    const int sc = blockIdx.x, cc = blockIdx.y;
    build_tables(nd, cwd, t);
    __syncthreads();
    int i0 = (int)(81.9 * (double)sc) - 2;
    if (i0 < 0) i0 = 0;
    i0 &= ~3;
    if (i0 > 4004) i0 = 4004;
    if (t < 40) {
        int l = 2 * sc + (t >= 20), jn = t % 20;
        double tq = 0.005 * ((double)(2 * l + 1) + nd[jn]);
        double sf = tq * 4095.0;
        int i = (int)sf; if (i > 4094) i = 4094;
        double a = sf - (double)i;
        if (a < 0.0) a = 0.0; if (a > 1.0) a = 1.0;
        qi[t] = i - i0;
        qa[t] = (float)a;
        qt[t] = (float)tq;
        qw[t] = (float)(0.005 * cwd[jn]);
    }
    __syncthreads();
    for (int idx = t; idx < 32 * 23; idx += 256) {    // x window 32 rows x 92
        int row = idx / 23, c4 = idx % 23;
        float4 v = *(const float4*)&x[(size_t)(cc * 32 + row) * NN + i0 + c4 * 4];
        float* d = &xw[row][c4 * 4];
        d[0] = v.x; d[1] = v.y; d[2] = v.z; d[3] = v.w;
    }
    __syncthreads();
    for (int idx = t; idx < 40 * 64; idx += 256) {    // E[s][m]
        int s = idx >> 6, m = idx & 63;
        double r = -(double)m * (double)qt[s];
        r -= floor(r);
        float fr = (float)r;
        e[0][s][m] = qw[s] * cos_rev(fr);
        e[1][s][m] = qw[s] * sin_rev(fr);
    }
    for (int idx = t; idx < 40 * 32; idx += 256) {    // interp -> xqT[q][r]
        int q = idx >> 5, r = idx & 31;
        float a = qa[q];
        xqT[q][r] = (1.f - a) * xw[r][qi[q]] + a * xw[r][qi[q] + 1];
    }
    __syncthreads();
    // GEMM: 32bc x 64m x 40s; thread tile 2bc x 4m
    const int mg = t & 15, bg = t >> 4;
    float aR[2][4] = {{0.f}}, aI[2][4] = {{0.f}};
    for (int s = 0; s < 40; ++s) {
        const float2 xv = *(const float2*)&xqT[s][bg * 2];
        const float4 er = *(const float4*)&e[0][s][mg * 4];
        const float4 ei = *(const float4*)&e[1][s][mg * 4];
#pragma unroll
        for (int p = 0; p < 2; ++p) {
            const float xm = p ? xv.y : xv.x;
            aR[p][0] += xm * er.x; aR[p][1] += xm * er.y;
            aR[p][2] += xm * er.z; aR[p][3] += xm * er.w;
            aI[p][0] += xm * ei.x; aI[p][1] += xm * ei.y;
            aI[p][2] += xm * ei.z; aI[p][3] += xm * ei.w;
        }
    }
#pragma unroll
    for (int p = 0; p < 2; ++p) {
        const size_t row = (size_t)sc * 512 + cc * 32 + bg * 2 + p;
        float4 vr, vi;
        vr.x = aR[p][0]; vr.y = aR[p][1]; vr.z = aR[p][2]; vr.w = aR[p][3];
        vi.x = aI[p][0]; vi.y = aI[p][1]; vi.z = aI[p][2]; vi.w = aI[p][3];
        *(float4*)&P[row * 128 + mg * 4]      = vr;
        *(float4*)&P[row * 128 + 64 + mg * 4] = vi;
    }
}

// ---------- reduce: X = sum_sc P[sc]; grid 512, 8 kc-groups ----------
__global__ __launch_bounds__(256) void k_reduce(float* __restrict__ ws,
                                                const float* __restrict__ P) {
    __shared__ float4 red[8][32];
    const int t = threadIdx.x;
    const int grp = t >> 5, o = t & 31;
    const int oid = blockIdx.x * 32 + o;           // 16384 float4 outputs
    const float4* P4 = (const float4*)P;
    float4 s = {0.f, 0.f, 0.f, 0.f};
    for (int kk = grp; kk < 50; kk += 8) {
        float4 v = P4[(size_t)kk * 16384 + oid];
        s.x += v.x; s.y += v.y; s.z += v.z; s.w += v.w;
    }
    red[grp][o] = s;
    __syncthreads();
    if (t < 32) {
        float4 r = red[0][t];
#pragma unroll
        for (int g = 1; g < 8; ++g) {
            float4 v = red[g][t];
            r.x += v.x; r.y += v.y; r.z += v.z; r.w += v.w;
        }
        int od = blockIdx.x * 32 + t;
        int bc = od >> 5, c4 = od & 31;
        if (c4 < 16) *(float4*)&ws[OFF_XRE + (size_t)bc * 64 + c4 * 4] = r;
        else         *(float4*)&ws[OFF_XIM + (size_t)bc * 64 + (c4 - 16) * 4] = r;
    }
}

// ---------- mixZ: grid 512 = (b, o); Y then Z for one (b,o) pair ----------
__global__ __launch_bounds__(256) void k_mixZ(const float* __restrict__ wr,
                                              const float* __restrict__ wi,
                                              float* __restrict__ ws) {
    __shared__ double nd[20], cwd[20];
    __shared__ float part[4][2][64];
    __shared__ float yt[2][64];
    __shared__ float sw0[NS3], sw1[NS3];
    __shared__ int   si0[NS3], si1[NS3];
    const int t = threadIdx.x;
    const int b = blockIdx.x >> 6, o = blockIdx.x & 63;
    build_tables(nd, cwd, t);
    __syncthreads();
    if (t < NS3) {
        int l = (t < 2) ? 49 : (t < 22 ? 50 : 51);
        int k = (t < 2) ? t : (t < 22 ? t - 2 : t - 13);
        double fq = -2048.0 + ((double)l + 0.5) * 40.95 + 20.475 * nd[k];
        int m0 = (int)floor(fq);
        float fr = (float)(fq - (double)m0);
        sw0[t] = (m0 >= 0 && m0 <= 63) ? (1.f - fr) : 0.f;
        sw1[t] = (m0 + 1 >= 0 && m0 + 1 <= 63) ? fr : 0.f;
        si0[t] = min(max(m0, 0), 63);
        si1[t] = min(max(m0 + 1, 0), 63);
    }
    const int m = t & 63, grp = t >> 6;
    float yr = 0.f, yi = 0.f;
#pragma unroll 4
    for (int i = grp * 16; i < grp * 16 + 16; ++i) {
        float xr = ws[OFF_XRE + (size_t)(b * 64 + i) * 64 + m];
        float xi = ws[OFF_XIM + (size_t)(b * 64 + i) * 64 + m];
        float a = wr[((size_t)i * 64 + o) * 64 + m];
        float c = wi[((size_t)i * 64 + o) * 64 + m];
        yr += xr * a - xi * c;
        yi += xr * c + xi * a;
    }
    part[grp][0][m] = yr;
    part[grp][1][m] = yi;
    __syncthreads();
    if (t < 128) {
        int pr = t >> 6, mm = t & 63;
        yt[pr][mm] = ((part[0][pr][mm] + part[1][pr][mm]) +
                      (part[2][pr][mm] + part[3][pr][mm]));
    }
    __syncthreads();
    if (t < 2 * NS3) {
        int p = t >= NS3, s = t - p * NS3;
        float z = sw0[s] * yt[p][si0[s]] + sw1[s] * yt[p][si1[s]];
        ws[OFF_Z + (size_t)p * 512 * NSP + ((size_t)b * 64 + o) * NSP + s] = z;
    } else if (t < 2 * NS3 + 14) {
        int u = t - 2 * NS3;
        int p = u / 7, s = NS3 + u % 7;
        ws[OFF_Z + (size_t)p * 512 * NSP + ((size_t)b * 64 + o) * NSP + s] = 0.f;
    }
}

// ---------- stage 3: out[p][j] = sum_s Re(Z[p][s] * wf_s e^{2pi i fq_s t_j}) ----------
__global__ __launch_bounds__(256) void k_stage3(const float* __restrict__ ws,
                                                float* __restrict__ out) {
    __shared__ double nd[20], cwd[20];
    __shared__ double sfq[NS3];
    __shared__ float  swf[NS3];
    __shared__ __align__(16) float zt[2][64][41];
    __shared__ __align__(16) float e2[2][NSP][64];
    const int t = threadIdx.x;
    const int jt = blockIdx.x, pc = blockIdx.y;
    build_tables(nd, cwd, t);
    __syncthreads();
    if (t < NS3) {
        int l = (t < 2) ? 49 : (t < 22 ? 50 : 51);
        int k = (t < 2) ? t : (t < 22 ? t - 2 : t - 13);
        sfq[t] = -2048.0 + ((double)l + 0.5) * 40.95 + 20.475 * nd[k];
        swf[t] = (float)(20.475 * cwd[k]);
    }
    for (int idx = t; idx < 2 * 64 * NSP; idx += 256) {
        int part = idx / (64 * NSP), rem = idx % (64 * NSP);
        int row = rem / NSP, s = rem % NSP;
        zt[part][row][s] =
            ws[OFF_Z + (size_t)part * 512 * NSP + ((size_t)pc * 64 + row) * NSP + s];
    }
    __syncthreads();
    const double inv4095 = 1.0 / 4095.0;
    for (int idx = t; idx < NSP * 64; idx += 256) {
        int s = idx >> 6, jl = idx & 63;
        float cr = 0.f, ci = 0.f;
        if (s < NS3) {
            double ph = sfq[s] * ((double)(jt * 64 + jl) * inv4095);
            ph -= floor(ph);
            float fr = (float)ph;
            cr = swf[s] * cos_rev(fr);
            ci = swf[s] * sin_rev(fr);
        }
        e2[0][s][jl] = cr;
        e2[1][s][jl] = ci;
    }
    __syncthreads();
    const int jg = t & 15, pg = t >> 4;
    float acc[4][4] = {{0.f}};
    for (int s0 = 0; s0 < NSP; s0 += 8) {
        float zr[4][8], zi[4][8];
#pragma unroll
        for (int p = 0; p < 4; ++p)
#pragma unroll
            for (int u = 0; u < 8; ++u) {
                zr[p][u] = zt[0][pg * 4 + p][s0 + u];
                zi[p][u] = zt[1][pg * 4 + p][s0 + u];
            }
#pragma unroll
        for (int u = 0; u < 8; ++u) {
            const float4 er = *(const float4*)&e2[0][s0 + u][jg * 4];
            const float4 ei = *(const float4*)&e2[1][s0 + u][jg * 4];
#pragma unroll
            for (int p = 0; p < 4; ++p) {
                acc[p][0] += zr[p][u] * er.x - zi[p][u] * ei.x;
                acc[p][1] += zr[p][u] * er.y - zi[p][u] * ei.y;
                acc[p][2] += zr[p][u] * er.z - zi[p][u] * ei.z;
                acc[p][3] += zr[p][u] * er.w - zi[p][u] * ei.w;
            }
        }
    }
#pragma unroll
    for (int p = 0; p < 4; ++p) {
        float4 r;
        r.x = acc[p][0]; r.y = acc[p][1]; r.z = acc[p][2]; r.w = acc[p][3];
        *(float4*)&out[(size_t)(pc * 64 + pg * 4 + p) * NN + jt * 64 + jg * 4] = r;
    }
}

extern "C" void kernel_launch(void* const* d_in, const int* in_sizes, int n_in,
                              void* d_out, int out_size, void* d_ws, size_t ws_size,
                              hipStream_t stream) {
    const float* x  = (const float*)d_in[0];
    const float* wr = (const float*)d_in[1];
    const float* wi = (const float*)d_in[2];
    float* out = (float*)d_out;
    float* ws  = (float*)d_ws;
    (void)in_sizes; (void)n_in; (void)out_size; (void)ws_size;   // needs ~13.5 MB

    float* P = ws + OFF_P;
    k_stage1<<<dim3(50, 16), 256, 0, stream>>>(x, P);
    k_reduce<<<512, 256, 0, stream>>>(ws, P);
    k_mixZ<<<512, 256, 0, stream>>>(wr, wi, ws);
    k_stage3<<<dim3(64, 8), 256, 0, stream>>>(ws, out);
}

// Round 8
// 31.096 us; speedup vs baseline: 8.1104x; 1.1943x over previous
//
#include <hip/hip_runtime.h>

// Spectral conv, fully factorized:
//   K1 (k_cft):  X[bc][m] = sum_l T[l][m] * (sum_k xq[bc][l,k] * F[k][m])
//                F = 20x64 const (trig once per block), T = exact twiddle.
//                One bc row per block -> no split-K partials, no reduce kernel.
//   K2 (k_mixZ): Y = channel-mix(X,W); Z[p][s] = sum_m Y[p][m] hat_s(m)
//   K3 (k_stage3): out = sum_s Re(Z * wf_s e^{2pi i fq_s t_j})
// 3 dispatches; total HBM ~20 MB.

#define NN 4096
#define C1_19 0.9863613034027223   // cos(pi/19)
#define NS3 33
#define NSP 40

// ws float offsets
#define OFF_XRE 0                  // X real [512*64]
#define OFF_XIM 32768
#define OFF_Z   65536              // Z [2][512][NSP]

__device__ __forceinline__ float sin_rev(float r) { return __builtin_amdgcn_sinf(r); }
__device__ __forceinline__ float cos_rev(float r) { return __builtin_amdgcn_cosf(r); }

// nd[k] = cos(pi k/19); cwd[k] = CC weight (endpoints halved). No libm.
// Contains one __syncthreads; caller must sync again before using cwd.
__device__ __forceinline__ void build_tables(double* nd, double* cwd, int t) {
    if (t == 0) {
        nd[0] = 1.0; nd[1] = C1_19;
        for (int k = 2; k < 20; ++k) nd[k] = 2.0 * C1_19 * nd[k - 1] - nd[k - 2];
    }
    __syncthreads();
    if (t < 20) {
        double v = 1.0;
        for (int j = 1; j <= 9; ++j) {
            int q = (2 * j * t) % 38; if (q > 19) q = 38 - q;   // cos(2pi j t/19)
            v -= 2.0 / (4.0 * j * j - 1.0) * nd[q];
        }
        double w = 2.0 * v / 19.0;
        if (t == 0 || t == 19) w *= 0.5;
        cwd[t] = w;
    }
}

// ---------- K1: full CFT, one bc row per block ----------
__global__ __launch_bounds__(256) void k_cft(const float* __restrict__ x,
                                             float* __restrict__ ws) {
    __shared__ double nd[20], cwd[20];
    __shared__ __align__(16) float xs[NN];          // 16 KB: one x row
    __shared__ __align__(16) float xq[2000];        // 8 KB: interp at cheb nodes
    __shared__ __align__(16) float Fri[20][64][2];  // 10.25 KB: F interleaved re,im
    __shared__ float red[4][64][2];
    const int t = threadIdx.x;
    const int bc = blockIdx.x;
    build_tables(nd, cwd, t);
    // stage x row (coalesced float4)
#pragma unroll
    for (int it = 0; it < 4; ++it) {
        int c4 = it * 256 + t;
        *(float4*)&xs[c4 * 4] = *(const float4*)&x[(size_t)bc * NN + c4 * 4];
    }
    __syncthreads();                 // nd/cwd + xs ready
    // F[k][m] = 0.005*w_k * exp(-2pi i * 0.005*m*node_k)
    for (int idx = t; idx < 1280; idx += 256) {
        int k = idx >> 6, m = idx & 63;
        double r = -0.005 * nd[k] * (double)m;
        r -= floor(r);
        float fr = (float)r;
        float w = (float)(0.005 * cwd[k]);
        Fri[k][m][0] = w * cos_rev(fr);
        Fri[k][m][1] = w * sin_rev(fr);
    }
    // xq: interp x onto the 2000 Chebyshev quadrature nodes
#pragma unroll
    for (int it = 0; it < 8; ++it) {
        int node = it * 256 + t;
        if (node < 2000) {
            int l = node / 20, k = node - l * 20;
            double tq = 0.005 * ((double)(2 * l + 1) + nd[k]);
            double sf = tq * 4095.0;
            int i = (int)sf; if (i > 4094) i = 4094;
            double a = sf - (double)i;
            if (a < 0.0) a = 0.0; if (a > 1.0) a = 1.0;
            float af = (float)a;
            xq[node] = (1.f - af) * xs[i] + af * xs[i + 1];
        }
    }
    __syncthreads();
    // per-lane F column into registers (20 complex)
    const int m = t & 63, grp = t >> 6;
    float Fre[20], Fim[20];
#pragma unroll
    for (int k = 0; k < 20; ++k) {
        Fre[k] = Fri[k][m][0];
        Fim[k] = Fri[k][m][1];
    }
    // main loop: 25 segments per thread-group; exact twiddle per l
    float ar = 0.f, ai = 0.f;
    for (int l = grp * 25; l < grp * 25 + 25; ++l) {
        const float4* q4 = (const float4*)&xq[l * 20];   // wave-uniform addr
        float ur = 0.f, ui = 0.f;
#pragma unroll
        for (int c = 0; c < 5; ++c) {
            float4 q = q4[c];
            ur += q.x * Fre[c * 4]     + q.y * Fre[c * 4 + 1]
                + q.z * Fre[c * 4 + 2] + q.w * Fre[c * 4 + 3];
            ui += q.x * Fim[c * 4]     + q.y * Fim[c * 4 + 1]
                + q.z * Fim[c * 4 + 2] + q.w * Fim[c * 4 + 3];
        }
        double r = -(double)(m * (2 * l + 1)) / 200.0;   // twiddle phase / 2pi
        r -= floor(r);
        float fr = (float)r;
        float tr = cos_rev(fr), ti = sin_rev(fr);
        ar += tr * ur - ti * ui;
        ai += tr * ui + ti * ur;
    }
    red[grp][m][0] = ar;
    red[grp][m][1] = ai;
    __syncthreads();
    if (t < 64) {
        float sr = (red[0][t][0] + red[1][t][0]) + (red[2][t][0] + red[3][t][0]);
        float si = (red[0][t][1] + red[1][t][1]) + (red[2][t][1] + red[3][t][1]);
        ws[OFF_XRE + (size_t)bc * 64 + t] = sr;
        ws[OFF_XIM + (size_t)bc * 64 + t] = si;
    }
}

// ---------- K2: mixZ; grid 512 = (b major, o minor) ----------
__global__ __launch_bounds__(256) void k_mixZ(const float* __restrict__ wr,
                                              const float* __restrict__ wi,
                                              float* __restrict__ ws) {
    __shared__ double nd[20], cwd[20];
    __shared__ float part[4][2][64];
    __shared__ float yt[2][64];
    __shared__ float sw0[NS3], sw1[NS3];
    __shared__ int   si0[NS3], si1[NS3];
    const int t = threadIdx.x;
    const int b = blockIdx.x >> 6, o = blockIdx.x & 63;
    build_tables(nd, cwd, t);
    __syncthreads();
    if (t < NS3) {
        int l = (t < 2) ? 49 : (t < 22 ? 50 : 51);
        int k = (t < 2) ? t : (t < 22 ? t - 2 : t - 13);
        double fq = -2048.0 + ((double)l + 0.5) * 40.95 + 20.475 * nd[k];
        int m0 = (int)floor(fq);
        float fr = (float)(fq - (double)m0);
        sw0[t] = (m0 >= 0 && m0 <= 63) ? (1.f - fr) : 0.f;
        sw1[t] = (m0 + 1 >= 0 && m0 + 1 <= 63) ? fr : 0.f;
        si0[t] = min(max(m0, 0), 63);
        si1[t] = min(max(m0 + 1, 0), 63);
    }
    const int m = t & 63, grp = t >> 6;
    float yr = 0.f, yi = 0.f;
#pragma unroll 4
    for (int i = grp * 16; i < grp * 16 + 16; ++i) {
        float xr = ws[OFF_XRE + (size_t)(b * 64 + i) * 64 + m];
        float xi = ws[OFF_XIM + (size_t)(b * 64 + i) * 64 + m];
        float a = wr[((size_t)i * 64 + o) * 64 + m];
        float c = wi[((size_t)i * 64 + o) * 64 + m];
        yr += xr * a - xi * c;
        yi += xr * c + xi * a;
    }
    part[grp][0][m] = yr;
    part[grp][1][m] = yi;
    __syncthreads();
    if (t < 128) {
        int pr = t >> 6, mm = t & 63;
        yt[pr][mm] = ((part[0][pr][mm] + part[1][pr][mm]) +
                      (part[2][pr][mm] + part[3][pr][mm]));
    }
    __syncthreads();
    if (t < 2 * NS3) {
        int p = t >= NS3, s = t - p * NS3;
        float z = sw0[s] * yt[p][si0[s]] + sw1[s] * yt[p][si1[s]];
        ws[OFF_Z + (size_t)p * 512 * NSP + ((size_t)b * 64 + o) * NSP + s] = z;
    } else if (t < 2 * NS3 + 14) {
        int u = t - 2 * NS3;
        int p = u / 7, s = NS3 + u % 7;
        ws[OFF_Z + (size_t)p * 512 * NSP + ((size_t)b * 64 + o) * NSP + s] = 0.f;
    }
}

// ---------- K3: out[p][j] = sum_s Re(Z[p][s] * wf_s e^{2pi i fq_s t_j}) ----------
__global__ __launch_bounds__(256) void k_stage3(const float* __restrict__ ws,
                                                float* __restrict__ out) {
    __shared__ double nd[20], cwd[20];
    __shared__ double sfq[NS3];
    __shared__ float  swf[NS3];
    __shared__ __align__(16) float zt[2][64][41];
    __shared__ __align__(16) float e2[2][NSP][64];
    const int t = threadIdx.x;
    const int jt = blockIdx.x, pc = blockIdx.y;
    build_tables(nd, cwd, t);
    __syncthreads();
    if (t < NS3) {
        int l = (t < 2) ? 49 : (t < 22 ? 50 : 51);
        int k = (t < 2) ? t : (t < 22 ? t - 2 : t - 13);
        sfq[t] = -2048.0 + ((double)l + 0.5) * 40.95 + 20.475 * nd[k];
        swf[t] = (float)(20.475 * cwd[k]);
    }
    for (int idx = t; idx < 2 * 64 * NSP; idx += 256) {
        int part = idx / (64 * NSP), rem = idx % (64 * NSP);
        int row = rem / NSP, s = rem % NSP;
        zt[part][row][s] =
            ws[OFF_Z + (size_t)part * 512 * NSP + ((size_t)pc * 64 + row) * NSP + s];
    }
    __syncthreads();
    const double inv4095 = 1.0 / 4095.0;
    for (int idx = t; idx < NSP * 64; idx += 256) {
        int s = idx >> 6, jl = idx & 63;
        float cr = 0.f, ci = 0.f;
        if (s < NS3) {
            double ph = sfq[s] * ((double)(jt * 64 + jl) * inv4095);
            ph -= floor(ph);
            float fr = (float)ph;
            cr = swf[s] * cos_rev(fr);
            ci = swf[s] * sin_rev(fr);
        }
        e2[0][s][jl] = cr;
        e2[1][s][jl] = ci;
    }
    __syncthreads();
    const int jg = t & 15, pg = t >> 4;
    float acc[4][4] = {{0.f}};
    for (int s0 = 0; s0 < NSP; s0 += 8) {
        float zr[4][8], zi[4][8];
#pragma unroll
        for (int p = 0; p < 4; ++p)
#pragma unroll
            for (int u = 0; u < 8; ++u) {
                zr[p][u] = zt[0][pg * 4 + p][s0 + u];
                zi[p][u] = zt[1][pg * 4 + p][s0 + u];
            }
#pragma unroll
        for (int u = 0; u < 8; ++u) {
            const float4 er = *(const float4*)&e2[0][s0 + u][jg * 4];
            const float4 ei = *(const float4*)&e2[1][s0 + u][jg * 4];
#pragma unroll
            for (int p = 0; p < 4; ++p) {
                acc[p][0] += zr[p][u] * er.x - zi[p][u] * ei.x;
                acc[p][1] += zr[p][u] * er.y - zi[p][u] * ei.y;
                acc[p][2] += zr[p][u] * er.z - zi[p][u] * ei.z;
                acc[p][3] += zr[p][u] * er.w - zi[p][u] * ei.w;
            }
        }
    }
#pragma unroll
    for (int p = 0; p < 4; ++p) {
        float4 r;
        r.x = acc[p][0]; r.y = acc[p][1]; r.z = acc[p][2]; r.w = acc[p][3];
        *(float4*)&out[(size_t)(pc * 64 + pg * 4 + p) * NN + jt * 64 + jg * 4] = r;
    }
}

extern "C" void kernel_launch(void* const* d_in, const int* in_sizes, int n_in,
                              void* d_out, int out_size, void* d_ws, size_t ws_size,
                              hipStream_t stream) {
    const float* x  = (const float*)d_in[0];
    const float* wr = (const float*)d_in[1];
    const float* wi = (const float*)d_in[2];
    float* out = (float*)d_out;
    float* ws  = (float*)d_ws;
    (void)in_sizes; (void)n_in; (void)out_size; (void)ws_size;   // needs ~0.5 MB

    k_cft<<<512, 256, 0, stream>>>(x, ws);
    k_mixZ<<<512, 256, 0, stream>>>(wr, wi, ws);
    k_stage3<<<dim3(64, 8), 256, 0, stream>>>(ws, out);
}